// Round 13
// baseline (262.416 us; speedup 1.0000x reference)
//
#include <hip/hip_runtime.h>
#include <hip/hip_bf16.h>

#define N_NODES 150000
#define N_EDGES 2400000
#define DIM     64
#define MAXDEG  64

#define NB      256     // buckets
#define NPB     587     // nodes per bucket (256*587 = 150272 >= N_NODES)
#define NSHARD  4       // record-region shards per bucket
#define CAPS    2816    // capacity per (bucket,shard); mean 2344, sd ~48 (9.7 sigma)
#define BINBLK  1024    // binning blocks; shard = blockIdx & 3; 4 blocks/CU
#define BINTHR  512
#define EPB     ((N_EDGES + BINBLK - 1) / BINBLK)   // 2344 edges per block

// ---------------------------------------------------------------------------
// 14-bit float: 5-bit exp (bias 104 -> 2^-23..2^8.99), 9-bit mantissa, RTE.
// ---------------------------------------------------------------------------
__device__ __forceinline__ unsigned enc14(float v) {
    unsigned b = __float_as_uint(v);
    b += (1u << 13);
    int e5 = (int)((b >> 23) & 0xFF) - 104;
    if (e5 <= 0) return 0u;
    if (e5 > 31) e5 = 31;
    return ((unsigned)e5 << 9) | ((b >> 14) & 0x1FFu);
}
__device__ __forceinline__ float dec14(unsigned w) {
    return __uint_as_float((w << 14) + (104u << 23));
}
__device__ __forceinline__ unsigned packbf(float a, float b) {
    unsigned ua = __float_as_uint(a), ub = __float_as_uint(b);
    ua += 0x7FFFu + ((ua >> 16) & 1u);
    ub += 0x7FFFu + ((ub >> 16) & 1u);
    return (ua >> 16) | (ub & 0xFFFF0000u);
}
__device__ __forceinline__ float bflo(unsigned v) { return __uint_as_float(v << 16); }
__device__ __forceinline__ float bfhi(unsigned v) { return __uint_as_float(v & 0xFFFF0000u); }

// ---------------------------------------------------------------------------
// Single-pass dual-stream binning + fused emb->bf16 conversion tail.
// ~36.5 KB LDS -> 4 blocks/CU (32 waves). shard = blockIdx & 3.
// recT record: uint2 { (t<<14)|v14 , f };  recF record: (f<<14)|v14
// ---------------------------------------------------------------------------
__global__ __launch_bounds__(BINTHR) void binA_kernel(const float* __restrict__ attrs,
                                                      const int* __restrict__ frm,
                                                      const int* __restrict__ to,
                                                      unsigned* __restrict__ gcntT,
                                                      unsigned* __restrict__ gcntF,
                                                      uint2* __restrict__ recT,
                                                      unsigned* __restrict__ recF,
                                                      const float* __restrict__ emb,
                                                      unsigned* __restrict__ embB) {
    __shared__ unsigned histT[NB], histF[NB], baseT[NB], baseF[NB];
    __shared__ unsigned gBaseT[NB], gBaseF[NB], curT[NB], curF[NB];
    __shared__ uint2    bufT[EPB];      // 18.75 KB
    __shared__ unsigned bufF[EPB];      // 9.4 KB

    int tid = threadIdx.x;
    int e0 = blockIdx.x * EPB;
    int e1 = e0 + EPB; if (e1 > N_EDGES) e1 = N_EDGES;
    int n = e1 - e0;
    unsigned shard = blockIdx.x & (NSHARD - 1);

    for (int i = tid; i < NB; i += BINTHR) {
        histT[i] = 0u; histF[i] = 0u; curT[i] = 0u; curF[i] = 0u;
    }
    __syncthreads();

    // ---- pass 1: both histograms in one sweep ----
    for (int e = e0 + tid; e < e1; e += BINTHR) {
        atomicAdd(&histT[(unsigned)to[e] / NPB], 1u);
        atomicAdd(&histF[(unsigned)frm[e] / NPB], 1u);
    }
    __syncthreads();

    // ---- dual inclusive scan (Hillis-Steele), then exclusive + reserve ----
    if (tid < NB) { baseT[tid] = histT[tid]; baseF[tid] = histF[tid]; }
    __syncthreads();
    for (int off = 1; off < NB; off <<= 1) {
        unsigned vT = 0u, vF = 0u;
        if (tid < NB) {
            vT = baseT[tid]; vF = baseF[tid];
            if (tid >= off) { vT += baseT[tid - off]; vF += baseF[tid - off]; }
        }
        __syncthreads();
        if (tid < NB) { baseT[tid] = vT; baseF[tid] = vF; }
        __syncthreads();
    }
    if (tid < NB) {
        unsigned hT = histT[tid], hF = histF[tid];
        baseT[tid] -= hT;                      // exclusive
        baseF[tid] -= hF;
        gBaseT[tid] = hT ? atomicAdd(&gcntT[tid * NSHARD + shard], hT) : 0u;
        gBaseF[tid] = hF ? atomicAdd(&gcntF[tid * NSHARD + shard], hF) : 0u;
    }
    __syncthreads();

    // ---- pass 2: scatter both streams into LDS (expf once per edge) ----
    for (int e = e0 + tid; e < e1; e += BINTHR) {
        unsigned t = (unsigned)to[e], f = (unsigned)frm[e];
        unsigned v14 = enc14(expf(attrs[e]));
        unsigned bT = t / NPB;
        bufT[baseT[bT] + atomicAdd(&curT[bT], 1u)] = make_uint2((t << 14) | v14, f);
        unsigned bF = f / NPB;
        bufF[baseF[bF] + atomicAdd(&curF[bF], 1u)] = (f << 14) | v14;
    }
    __syncthreads();

    // ---- coalesced copy-out ----
    for (int s = tid; s < n; s += BINTHR) {
        uint2 r = bufT[s];
        unsigned b = (r.x >> 14) / NPB;
        unsigned dst = gBaseT[b] + ((unsigned)s - baseT[b]);
        if (dst < CAPS) recT[(size_t)(b * NSHARD + shard) * CAPS + dst] = r;
    }
    for (int s = tid; s < n; s += BINTHR) {
        unsigned r = bufF[s];
        unsigned b = (r >> 14) / NPB;
        unsigned dst = gBaseF[b] + ((unsigned)s - baseF[b]);
        if (dst < CAPS) recF[(size_t)(b * NSHARD + shard) * CAPS + dst] = r;
    }

    // ---- fused cvt tail: emb -> bf16 embB (grid-stride, no sync needed) ----
    const int total4 = N_NODES * DIM / 4;
    for (int i = blockIdx.x * BINTHR + tid; i < total4; i += BINBLK * BINTHR) {
        float4 v = reinterpret_cast<const float4*>(emb)[i];
        uint2 p;
        p.x = packbf(v.x, v.y);
        p.y = packbf(v.z, v.w);
        reinterpret_cast<uint2*>(embB)[i] = p;
    }
}

// ---------------------------------------------------------------------------
// Pass B (by-src): s_out[f] = sum exp(a), LDS accumulation. Unchanged.
// ---------------------------------------------------------------------------
__global__ __launch_bounds__(1024) void sumF_kernel(const unsigned* __restrict__ recF,
                                                    const unsigned* __restrict__ gcntF,
                                                    float* __restrict__ s_out) {
    __shared__ float acc[NPB];
    int b = blockIdx.x;
    for (int i = threadIdx.x; i < NPB; i += blockDim.x) acc[i] = 0.f;
    __syncthreads();
    unsigned nodeBase = (unsigned)b * NPB;
    for (int s = 0; s < NSHARD; ++s) {
        unsigned n = gcntF[b * NSHARD + s];
        if (n > CAPS) n = CAPS;
        const unsigned* r = recF + (size_t)(b * NSHARD + s) * CAPS;
        for (unsigned i = threadIdx.x; i < n; i += blockDim.x) {
            unsigned w = r[i];
            atomicAdd(&acc[(w >> 14) - nodeBase], dec14(w & 0x3FFFu));
        }
    }
    __syncthreads();
    for (int i = threadIdx.x; i < NPB && (int)nodeBase + i < N_NODES; i += blockDim.x)
        s_out[nodeBase + i] = acc[i];
}

// ---------------------------------------------------------------------------
// Pass B (by-dest): s_in (LDS) -> norm + slot scatter into padded 64-slot
// rows -> zero-pad to multiple of 8. Unchanged.
// ---------------------------------------------------------------------------
__global__ __launch_bounds__(1024) void buildT_kernel(const uint2* __restrict__ recT,
                                                      const unsigned* __restrict__ gcntT,
                                                      const float* __restrict__ s_out,
                                                      unsigned* __restrict__ edges,
                                                      int* __restrict__ fill) {
    __shared__ float    sinL[NPB];
    __shared__ unsigned filL[NPB];
    int b = blockIdx.x;
    for (int i = threadIdx.x; i < NPB; i += blockDim.x) { sinL[i] = 0.f; filL[i] = 0u; }
    __syncthreads();
    unsigned nodeBase = (unsigned)b * NPB;
    for (int s = 0; s < NSHARD; ++s) {          // phase 1: s_in
        unsigned n = gcntT[b * NSHARD + s];
        if (n > CAPS) n = CAPS;
        const uint2* r = recT + (size_t)(b * NSHARD + s) * CAPS;
        for (unsigned i = threadIdx.x; i < n; i += blockDim.x) {
            uint2 w = r[i];
            atomicAdd(&sinL[(w.x >> 14) - nodeBase], dec14(w.x & 0x3FFFu));
        }
    }
    __syncthreads();
    for (int s = 0; s < NSHARD; ++s) {          // phase 2: norm + scatter
        unsigned n = gcntT[b * NSHARD + s];
        if (n > CAPS) n = CAPS;
        const uint2* r = recT + (size_t)(b * NSHARD + s) * CAPS;
        for (unsigned i = threadIdx.x; i < n; i += blockDim.x) {
            uint2 w = r[i];
            unsigned t = w.x >> 14;
            float ea = dec14(w.x & 0x3FFFu);
            unsigned f = w.y;
            float nrm = ea * rsqrtf(sinL[t - nodeBase] * s_out[f]);
            unsigned p = atomicAdd(&filL[t - nodeBase], 1u);
            if (p < MAXDEG) edges[(size_t)t * MAXDEG + p] = (f << 14) | enc14(nrm);
        }
    }
    __syncthreads();
    for (int i = threadIdx.x; i < NPB && (int)nodeBase + i < N_NODES; i += blockDim.x) {
        unsigned n = filL[i]; if (n > MAXDEG) n = MAXDEG;
        unsigned n8 = (n + 7u) & ~7u; if (n8 > MAXDEG) n8 = MAXDEG;
        for (unsigned p = n; p < n8; ++p)
            edges[(size_t)(nodeBase + i) * MAXDEG + p] = 0u;  // ~1.2e-7 payload: negligible
        fill[nodeBase + i] = (int)n8;
    }
}

// ---------------------------------------------------------------------------
// Layer (quarter-split + depth-2 pipeline — best measured variant, unchanged):
// FINAL: out = 0.25*(embB + x1 + x2 + acc); else y (bf16) only.
// ---------------------------------------------------------------------------
#define QSEL(W, V4) { unsigned t1_ = (q & 1) ? (V4).y : (V4).x; \
                      unsigned t2_ = (q & 1) ? (V4).w : (V4).z; \
                      W = (q & 2) ? t2_ : t1_; }
#define QFMA(N, X) { ax += (N) * bflo((X).x); ay += (N) * bfhi((X).x); \
                     az += (N) * bflo((X).y); aw_ += (N) * bfhi((X).y); }

template<bool FINAL>
__global__ __launch_bounds__(256) void layer_kernel(const uint2* __restrict__ xw2,
                                                    const unsigned* __restrict__ edges,
                                                    const int* __restrict__ fill,
                                                    uint2* __restrict__ yw2,
                                                    const uint2* __restrict__ embB2,
                                                    const uint2* __restrict__ x1w2,
                                                    const uint2* __restrict__ x2w2,
                                                    float* __restrict__ out) {
    int node = blockIdx.x * 4 + (threadIdx.x >> 6);   // grid covers exactly N_NODES
    int nodeU = __builtin_amdgcn_readfirstlane(node);
    int lane = threadIdx.x & 63;
    int q  = lane >> 4;          // quarter -> edge j+q within each group of 4
    int p4 = lane & 15;          // uint2 index: dims 4p4..4p4+3
    int cnt = fill[nodeU];
    const uint4* erow4 = reinterpret_cast<const uint4*>(edges + (size_t)nodeU * MAXDEG);
    float ax = 0.f, ay = 0.f, az = 0.f, aw_ = 0.f;
    int nIter = cnt >> 3;        // 8-edge groups (cnt pre-padded to x8)
    if (nIter > 0) {
        uint4 A = erow4[0], B = erow4[1];
        unsigned w0, w1;
        QSEL(w0, A); QSEL(w1, B);
        uint2 xa = xw2[(w0 >> 14) * 16 + p4];
        uint2 xb = xw2[(w1 >> 14) * 16 + p4];
        unsigned v0 = 0u, v1 = 0u;
        uint2 xc = make_uint2(0u, 0u), xd = make_uint2(0u, 0u);
        if (nIter > 1) {
            uint4 C = erow4[2], D = erow4[3];
            QSEL(v0, C); QSEL(v1, D);
            xc = xw2[(v0 >> 14) * 16 + p4];
            xd = xw2[(v1 >> 14) * 16 + p4];
        }
        for (int g = 2; g < nIter; ++g) {
            uint4 E = erow4[2 * g], F = erow4[2 * g + 1];
            unsigned u0, u1;
            QSEL(u0, E); QSEL(u1, F);
            uint2 xe = xw2[(u0 >> 14) * 16 + p4];
            uint2 xf = xw2[(u1 >> 14) * 16 + p4];
            float n0 = dec14(w0 & 0x3FFFu), n1 = dec14(w1 & 0x3FFFu);
            QFMA(n0, xa); QFMA(n1, xb);
            w0 = v0; w1 = v1; xa = xc; xb = xd;
            v0 = u0; v1 = u1; xc = xe; xd = xf;
        }
        { float n0 = dec14(w0 & 0x3FFFu), n1 = dec14(w1 & 0x3FFFu);
          QFMA(n0, xa); QFMA(n1, xb); }
        if (nIter > 1) {
            float n0 = dec14(v0 & 0x3FFFu), n1 = dec14(v1 & 0x3FFFu);
            QFMA(n0, xc); QFMA(n1, xd);
        }
    }
    ax += __shfl_xor(ax, 16, 64); ay += __shfl_xor(ay, 16, 64);
    az += __shfl_xor(az, 16, 64); aw_ += __shfl_xor(aw_, 16, 64);
    ax += __shfl_xor(ax, 32, 64); ay += __shfl_xor(ay, 32, 64);
    az += __shfl_xor(az, 32, 64); aw_ += __shfl_xor(aw_, 32, 64);
    if (lane < 16) {
        int o = nodeU * 16 + p4;
        if (!FINAL) {
            yw2[o] = make_uint2(packbf(ax, ay), packbf(az, aw_));
        } else {
            uint2 e = embB2[o], u1 = x1w2[o], u2 = x2w2[o];
            float4 r;
            r.x = 0.25f * (bflo(e.x) + bflo(u1.x) + bflo(u2.x) + ax);
            r.y = 0.25f * (bfhi(e.x) + bfhi(u1.x) + bfhi(u2.x) + ay);
            r.z = 0.25f * (bflo(e.y) + bflo(u1.y) + bflo(u2.y) + az);
            r.w = 0.25f * (bfhi(e.y) + bfhi(u1.y) + bfhi(u2.y) + aw_);
            reinterpret_cast<float4*>(out)[o] = r;
        }
    }
}

extern "C" void kernel_launch(void* const* d_in, const int* in_sizes, int n_in,
                              void* d_out, int out_size, void* d_ws, size_t ws_size,
                              hipStream_t stream) {
    const float* emb   = (const float*)d_in[0];
    const int*   eidx  = (const int*)d_in[1];
    const float* attrs = (const float*)d_in[2];
    const int* frm = eidx;
    const int* to  = eidx + N_EDGES;
    float* out = (float*)d_out;

    // ---- workspace layout (~93.5 MB; recT/recF overlay xA/xB) ----
    float*    s_out = (float*)d_ws;                               // 600 KB
    int*      fill  = (int*)(s_out + N_NODES);                    // 600 KB
    unsigned* gcntT = (unsigned*)(fill + N_NODES);                // 4 KB
    unsigned* gcntF = gcntT + NB * NSHARD;                        // 4 KB
    unsigned* edges = gcntF + NB * NSHARD;                        // 38.4 MB
    unsigned* embB  = edges + (size_t)N_NODES * MAXDEG;           // 19.2 MB
    unsigned* U     = embB + (size_t)N_NODES * 32;                // union region
    uint2*    recT  = (uint2*)U;                                  // 23.07 MB
    unsigned* recF  = (unsigned*)(recT + (size_t)NB * NSHARD * CAPS); // 11.53 MB
    unsigned* xA    = U;                                          // overlays recT/recF
    unsigned* xB    = xA + (size_t)N_NODES * 32;

    const int gN  = N_NODES / 4;   // 37500, exact

    hipMemsetAsync(gcntT, 0, 2 * NB * NSHARD * sizeof(unsigned), stream);
    binA_kernel<<<BINBLK, BINTHR, 0, stream>>>(attrs, frm, to, gcntT, gcntF,
                                               recT, recF, emb, embB);
    sumF_kernel<<<NB, 1024, 0, stream>>>(recF, gcntF, s_out);
    buildT_kernel<<<NB, 1024, 0, stream>>>(recT, gcntT, s_out, edges, fill);

    const uint2* embB2 = (const uint2*)embB;
    uint2* xA2 = (uint2*)xA;
    uint2* xB2 = (uint2*)xB;

    layer_kernel<false><<<gN, 256, 0, stream>>>(embB2, edges, fill, xA2,
                                                embB2, xA2, xB2, out);
    layer_kernel<false><<<gN, 256, 0, stream>>>((const uint2*)xA, edges, fill, xB2,
                                                embB2, xA2, xB2, out);
    layer_kernel<true ><<<gN, 256, 0, stream>>>((const uint2*)xB, edges, fill, xA2,
                                                embB2, xA2, xB2, out);
}

// Round 14
// 245.144 us; speedup vs baseline: 1.0705x; 1.0705x over previous
//
#include <hip/hip_runtime.h>
#include <hip/hip_bf16.h>

#define N_NODES 150000
#define N_EDGES 2400000
#define DIM     64
#define MAXDEG  64

#define NB      256     // buckets
#define NPB     587     // nodes per bucket (256*587 = 150272 >= N_NODES)
#define NSHARD  4       // record-region shards per bucket
#define CAPS    2816    // capacity per (bucket,shard); mean 2344, sd ~48 (9.7 sigma)
#define BINBLK  512     // binning blocks; shard = blockIdx & 3 (R12 best: long runs)
#define BINTHR  1024    // 1024 thr/block -> 2 blocks/CU x 16 waves = full CU
#define EPB     ((N_EDGES + BINBLK - 1) / BINBLK)   // 4688 edges per block

// ---------------------------------------------------------------------------
// 14-bit float: 5-bit exp (bias 104 -> 2^-23..2^8.99), 9-bit mantissa, RTE.
// ---------------------------------------------------------------------------
__device__ __forceinline__ unsigned enc14(float v) {
    unsigned b = __float_as_uint(v);
    b += (1u << 13);
    int e5 = (int)((b >> 23) & 0xFF) - 104;
    if (e5 <= 0) return 0u;
    if (e5 > 31) e5 = 31;
    return ((unsigned)e5 << 9) | ((b >> 14) & 0x1FFu);
}
__device__ __forceinline__ float dec14(unsigned w) {
    return __uint_as_float((w << 14) + (104u << 23));
}
__device__ __forceinline__ unsigned packbf(float a, float b) {
    unsigned ua = __float_as_uint(a), ub = __float_as_uint(b);
    ua += 0x7FFFu + ((ua >> 16) & 1u);
    ub += 0x7FFFu + ((ub >> 16) & 1u);
    return (ua >> 16) | (ub & 0xFFFF0000u);
}
__device__ __forceinline__ float bflo(unsigned v) { return __uint_as_float(v << 16); }
__device__ __forceinline__ float bfhi(unsigned v) { return __uint_as_float(v & 0xFFFF0000u); }

// ---------------------------------------------------------------------------
// Single-pass dual-stream binning + fused emb->bf16 conversion tail.
// ~64.5 KB LDS -> 2 blocks/CU x 16 waves = 32 waves/CU (full).
// recT record: uint2 { (t<<14)|v14 , f };  recF record: (f<<14)|v14
// ---------------------------------------------------------------------------
__global__ __launch_bounds__(BINTHR) void binA_kernel(const float* __restrict__ attrs,
                                                      const int* __restrict__ frm,
                                                      const int* __restrict__ to,
                                                      unsigned* __restrict__ gcntT,
                                                      unsigned* __restrict__ gcntF,
                                                      uint2* __restrict__ recT,
                                                      unsigned* __restrict__ recF,
                                                      const float* __restrict__ emb,
                                                      unsigned* __restrict__ embB) {
    __shared__ unsigned histT[NB], histF[NB], baseT[NB], baseF[NB];
    __shared__ unsigned gBaseT[NB], gBaseF[NB], curT[NB], curF[NB];
    __shared__ uint2    bufT[EPB];      // 37.5 KB
    __shared__ unsigned bufF[EPB];      // 18.75 KB

    int tid = threadIdx.x;
    int e0 = blockIdx.x * EPB;
    int e1 = e0 + EPB; if (e1 > N_EDGES) e1 = N_EDGES;
    int n = e1 - e0;
    unsigned shard = blockIdx.x & (NSHARD - 1);

    for (int i = tid; i < NB; i += BINTHR) {
        histT[i] = 0u; histF[i] = 0u; curT[i] = 0u; curF[i] = 0u;
    }
    __syncthreads();

    // ---- pass 1: both histograms in one sweep ----
    for (int e = e0 + tid; e < e1; e += BINTHR) {
        atomicAdd(&histT[(unsigned)to[e] / NPB], 1u);
        atomicAdd(&histF[(unsigned)frm[e] / NPB], 1u);
    }
    __syncthreads();

    // ---- dual inclusive scan (Hillis-Steele), then exclusive + reserve ----
    if (tid < NB) { baseT[tid] = histT[tid]; baseF[tid] = histF[tid]; }
    __syncthreads();
    for (int off = 1; off < NB; off <<= 1) {
        unsigned vT = 0u, vF = 0u;
        if (tid < NB) {
            vT = baseT[tid]; vF = baseF[tid];
            if (tid >= off) { vT += baseT[tid - off]; vF += baseF[tid - off]; }
        }
        __syncthreads();
        if (tid < NB) { baseT[tid] = vT; baseF[tid] = vF; }
        __syncthreads();
    }
    if (tid < NB) {
        unsigned hT = histT[tid], hF = histF[tid];
        baseT[tid] -= hT;                      // exclusive
        baseF[tid] -= hF;
        gBaseT[tid] = hT ? atomicAdd(&gcntT[tid * NSHARD + shard], hT) : 0u;
        gBaseF[tid] = hF ? atomicAdd(&gcntF[tid * NSHARD + shard], hF) : 0u;
    }
    __syncthreads();

    // ---- pass 2: scatter both streams into LDS (expf once per edge) ----
    for (int e = e0 + tid; e < e1; e += BINTHR) {
        unsigned t = (unsigned)to[e], f = (unsigned)frm[e];
        unsigned v14 = enc14(expf(attrs[e]));
        unsigned bT = t / NPB;
        bufT[baseT[bT] + atomicAdd(&curT[bT], 1u)] = make_uint2((t << 14) | v14, f);
        unsigned bF = f / NPB;
        bufF[baseF[bF] + atomicAdd(&curF[bF], 1u)] = (f << 14) | v14;
    }
    __syncthreads();

    // ---- coalesced copy-out ----
    for (int s = tid; s < n; s += BINTHR) {
        uint2 r = bufT[s];
        unsigned b = (r.x >> 14) / NPB;
        unsigned dst = gBaseT[b] + ((unsigned)s - baseT[b]);
        if (dst < CAPS) recT[(size_t)(b * NSHARD + shard) * CAPS + dst] = r;
    }
    for (int s = tid; s < n; s += BINTHR) {
        unsigned r = bufF[s];
        unsigned b = (r >> 14) / NPB;
        unsigned dst = gBaseF[b] + ((unsigned)s - baseF[b]);
        if (dst < CAPS) recF[(size_t)(b * NSHARD + shard) * CAPS + dst] = r;
    }

    // ---- fused cvt tail: emb -> bf16 embB (grid-stride, no sync needed) ----
    const int total4 = N_NODES * DIM / 4;
    for (int i = blockIdx.x * BINTHR + tid; i < total4; i += BINBLK * BINTHR) {
        float4 v = reinterpret_cast<const float4*>(emb)[i];
        uint2 p;
        p.x = packbf(v.x, v.y);
        p.y = packbf(v.z, v.w);
        reinterpret_cast<uint2*>(embB)[i] = p;
    }
}

// ---------------------------------------------------------------------------
// Pass B (by-src): s_out[f] = sum exp(a), LDS accumulation. Unchanged.
// ---------------------------------------------------------------------------
__global__ __launch_bounds__(1024) void sumF_kernel(const unsigned* __restrict__ recF,
                                                    const unsigned* __restrict__ gcntF,
                                                    float* __restrict__ s_out) {
    __shared__ float acc[NPB];
    int b = blockIdx.x;
    for (int i = threadIdx.x; i < NPB; i += blockDim.x) acc[i] = 0.f;
    __syncthreads();
    unsigned nodeBase = (unsigned)b * NPB;
    for (int s = 0; s < NSHARD; ++s) {
        unsigned n = gcntF[b * NSHARD + s];
        if (n > CAPS) n = CAPS;
        const unsigned* r = recF + (size_t)(b * NSHARD + s) * CAPS;
        for (unsigned i = threadIdx.x; i < n; i += blockDim.x) {
            unsigned w = r[i];
            atomicAdd(&acc[(w >> 14) - nodeBase], dec14(w & 0x3FFFu));
        }
    }
    __syncthreads();
    for (int i = threadIdx.x; i < NPB && (int)nodeBase + i < N_NODES; i += blockDim.x)
        s_out[nodeBase + i] = acc[i];
}

// ---------------------------------------------------------------------------
// Pass B (by-dest): s_in (LDS) -> norm + slot scatter into padded 64-slot
// rows -> zero-pad to multiple of 8. Unchanged.
// ---------------------------------------------------------------------------
__global__ __launch_bounds__(1024) void buildT_kernel(const uint2* __restrict__ recT,
                                                      const unsigned* __restrict__ gcntT,
                                                      const float* __restrict__ s_out,
                                                      unsigned* __restrict__ edges,
                                                      int* __restrict__ fill) {
    __shared__ float    sinL[NPB];
    __shared__ unsigned filL[NPB];
    int b = blockIdx.x;
    for (int i = threadIdx.x; i < NPB; i += blockDim.x) { sinL[i] = 0.f; filL[i] = 0u; }
    __syncthreads();
    unsigned nodeBase = (unsigned)b * NPB;
    for (int s = 0; s < NSHARD; ++s) {          // phase 1: s_in
        unsigned n = gcntT[b * NSHARD + s];
        if (n > CAPS) n = CAPS;
        const uint2* r = recT + (size_t)(b * NSHARD + s) * CAPS;
        for (unsigned i = threadIdx.x; i < n; i += blockDim.x) {
            uint2 w = r[i];
            atomicAdd(&sinL[(w.x >> 14) - nodeBase], dec14(w.x & 0x3FFFu));
        }
    }
    __syncthreads();
    for (int s = 0; s < NSHARD; ++s) {          // phase 2: norm + scatter
        unsigned n = gcntT[b * NSHARD + s];
        if (n > CAPS) n = CAPS;
        const uint2* r = recT + (size_t)(b * NSHARD + s) * CAPS;
        for (unsigned i = threadIdx.x; i < n; i += blockDim.x) {
            uint2 w = r[i];
            unsigned t = w.x >> 14;
            float ea = dec14(w.x & 0x3FFFu);
            unsigned f = w.y;
            float nrm = ea * rsqrtf(sinL[t - nodeBase] * s_out[f]);
            unsigned p = atomicAdd(&filL[t - nodeBase], 1u);
            if (p < MAXDEG) edges[(size_t)t * MAXDEG + p] = (f << 14) | enc14(nrm);
        }
    }
    __syncthreads();
    for (int i = threadIdx.x; i < NPB && (int)nodeBase + i < N_NODES; i += blockDim.x) {
        unsigned n = filL[i]; if (n > MAXDEG) n = MAXDEG;
        unsigned n8 = (n + 7u) & ~7u; if (n8 > MAXDEG) n8 = MAXDEG;
        for (unsigned p = n; p < n8; ++p)
            edges[(size_t)(nodeBase + i) * MAXDEG + p] = 0u;  // ~1.2e-7 payload: negligible
        fill[nodeBase + i] = (int)n8;
    }
}

// ---------------------------------------------------------------------------
// Layer (quarter-split + depth-2 pipeline — best measured variant, unchanged):
// FINAL: out = 0.25*(embB + x1 + x2 + acc); else y (bf16) only.
// ---------------------------------------------------------------------------
#define QSEL(W, V4) { unsigned t1_ = (q & 1) ? (V4).y : (V4).x; \
                      unsigned t2_ = (q & 1) ? (V4).w : (V4).z; \
                      W = (q & 2) ? t2_ : t1_; }
#define QFMA(N, X) { ax += (N) * bflo((X).x); ay += (N) * bfhi((X).x); \
                     az += (N) * bflo((X).y); aw_ += (N) * bfhi((X).y); }

template<bool FINAL>
__global__ __launch_bounds__(256) void layer_kernel(const uint2* __restrict__ xw2,
                                                    const unsigned* __restrict__ edges,
                                                    const int* __restrict__ fill,
                                                    uint2* __restrict__ yw2,
                                                    const uint2* __restrict__ embB2,
                                                    const uint2* __restrict__ x1w2,
                                                    const uint2* __restrict__ x2w2,
                                                    float* __restrict__ out) {
    int node = blockIdx.x * 4 + (threadIdx.x >> 6);   // grid covers exactly N_NODES
    int nodeU = __builtin_amdgcn_readfirstlane(node);
    int lane = threadIdx.x & 63;
    int q  = lane >> 4;          // quarter -> edge j+q within each group of 4
    int p4 = lane & 15;          // uint2 index: dims 4p4..4p4+3
    int cnt = fill[nodeU];
    const uint4* erow4 = reinterpret_cast<const uint4*>(edges + (size_t)nodeU * MAXDEG);
    float ax = 0.f, ay = 0.f, az = 0.f, aw_ = 0.f;
    int nIter = cnt >> 3;        // 8-edge groups (cnt pre-padded to x8)
    if (nIter > 0) {
        uint4 A = erow4[0], B = erow4[1];
        unsigned w0, w1;
        QSEL(w0, A); QSEL(w1, B);
        uint2 xa = xw2[(w0 >> 14) * 16 + p4];
        uint2 xb = xw2[(w1 >> 14) * 16 + p4];
        unsigned v0 = 0u, v1 = 0u;
        uint2 xc = make_uint2(0u, 0u), xd = make_uint2(0u, 0u);
        if (nIter > 1) {
            uint4 C = erow4[2], D = erow4[3];
            QSEL(v0, C); QSEL(v1, D);
            xc = xw2[(v0 >> 14) * 16 + p4];
            xd = xw2[(v1 >> 14) * 16 + p4];
        }
        for (int g = 2; g < nIter; ++g) {
            uint4 E = erow4[2 * g], F = erow4[2 * g + 1];
            unsigned u0, u1;
            QSEL(u0, E); QSEL(u1, F);
            uint2 xe = xw2[(u0 >> 14) * 16 + p4];
            uint2 xf = xw2[(u1 >> 14) * 16 + p4];
            float n0 = dec14(w0 & 0x3FFFu), n1 = dec14(w1 & 0x3FFFu);
            QFMA(n0, xa); QFMA(n1, xb);
            w0 = v0; w1 = v1; xa = xc; xb = xd;
            v0 = u0; v1 = u1; xc = xe; xd = xf;
        }
        { float n0 = dec14(w0 & 0x3FFFu), n1 = dec14(w1 & 0x3FFFu);
          QFMA(n0, xa); QFMA(n1, xb); }
        if (nIter > 1) {
            float n0 = dec14(v0 & 0x3FFFu), n1 = dec14(v1 & 0x3FFFu);
            QFMA(n0, xc); QFMA(n1, xd);
        }
    }
    ax += __shfl_xor(ax, 16, 64); ay += __shfl_xor(ay, 16, 64);
    az += __shfl_xor(az, 16, 64); aw_ += __shfl_xor(aw_, 16, 64);
    ax += __shfl_xor(ax, 32, 64); ay += __shfl_xor(ay, 32, 64);
    az += __shfl_xor(az, 32, 64); aw_ += __shfl_xor(aw_, 32, 64);
    if (lane < 16) {
        int o = nodeU * 16 + p4;
        if (!FINAL) {
            yw2[o] = make_uint2(packbf(ax, ay), packbf(az, aw_));
        } else {
            uint2 e = embB2[o], u1 = x1w2[o], u2 = x2w2[o];
            float4 r;
            r.x = 0.25f * (bflo(e.x) + bflo(u1.x) + bflo(u2.x) + ax);
            r.y = 0.25f * (bfhi(e.x) + bfhi(u1.x) + bfhi(u2.x) + ay);
            r.z = 0.25f * (bflo(e.y) + bflo(u1.y) + bflo(u2.y) + az);
            r.w = 0.25f * (bfhi(e.y) + bfhi(u1.y) + bfhi(u2.y) + aw_);
            reinterpret_cast<float4*>(out)[o] = r;
        }
    }
}

extern "C" void kernel_launch(void* const* d_in, const int* in_sizes, int n_in,
                              void* d_out, int out_size, void* d_ws, size_t ws_size,
                              hipStream_t stream) {
    const float* emb   = (const float*)d_in[0];
    const int*   eidx  = (const int*)d_in[1];
    const float* attrs = (const float*)d_in[2];
    const int* frm = eidx;
    const int* to  = eidx + N_EDGES;
    float* out = (float*)d_out;

    // ---- workspace layout (~93.5 MB; recT/recF overlay xA/xB) ----
    float*    s_out = (float*)d_ws;                               // 600 KB
    int*      fill  = (int*)(s_out + N_NODES);                    // 600 KB
    unsigned* gcntT = (unsigned*)(fill + N_NODES);                // 4 KB
    unsigned* gcntF = gcntT + NB * NSHARD;                        // 4 KB
    unsigned* edges = gcntF + NB * NSHARD;                        // 38.4 MB
    unsigned* embB  = edges + (size_t)N_NODES * MAXDEG;           // 19.2 MB
    unsigned* U     = embB + (size_t)N_NODES * 32;                // union region
    uint2*    recT  = (uint2*)U;                                  // 23.07 MB
    unsigned* recF  = (unsigned*)(recT + (size_t)NB * NSHARD * CAPS); // 11.53 MB
    unsigned* xA    = U;                                          // overlays recT/recF
    unsigned* xB    = xA + (size_t)N_NODES * 32;

    const int gN  = N_NODES / 4;   // 37500, exact

    hipMemsetAsync(gcntT, 0, 2 * NB * NSHARD * sizeof(unsigned), stream);
    binA_kernel<<<BINBLK, BINTHR, 0, stream>>>(attrs, frm, to, gcntT, gcntF,
                                               recT, recF, emb, embB);
    sumF_kernel<<<NB, 1024, 0, stream>>>(recF, gcntF, s_out);
    buildT_kernel<<<NB, 1024, 0, stream>>>(recT, gcntT, s_out, edges, fill);

    const uint2* embB2 = (const uint2*)embB;
    uint2* xA2 = (uint2*)xA;
    uint2* xB2 = (uint2*)xB;

    layer_kernel<false><<<gN, 256, 0, stream>>>(embB2, edges, fill, xA2,
                                                embB2, xA2, xB2, out);
    layer_kernel<false><<<gN, 256, 0, stream>>>((const uint2*)xA, edges, fill, xB2,
                                                embB2, xA2, xB2, out);
    layer_kernel<true ><<<gN, 256, 0, stream>>>((const uint2*)xB, edges, fill, xA2,
                                                embB2, xA2, xB2, out);
}